// Round 8
// baseline (170.322 us; speedup 1.0000x reference)
//
#include <hip/hip_runtime.h>
#include <hip/hip_bf16.h>
#include <stdint.h>

typedef __bf16 bf16_t;
typedef __bf16 bf16x4 __attribute__((ext_vector_type(4)));
typedef __bf16 bf16x8 __attribute__((ext_vector_type(8)));
typedef float  f32x4  __attribute__((ext_vector_type(4)));

#define AS_GLOBAL __attribute__((address_space(1)))
#define AS_LDS    __attribute__((address_space(3)))

__device__ __forceinline__ void gload_lds16(const void* g, void* l) {
  __builtin_amdgcn_global_load_lds((const AS_GLOBAL void*)g,
                                   (AS_LDS void*)l, 16, 0, 0);
}

// ---------------- K0a: f32 -> bf16 elementwise (8 elems/thread) ----------------
__global__ void cvt_f32_bf16_kernel(const float* __restrict__ in,
                                    bf16_t* __restrict__ out) {
  const int i = blockIdx.x * blockDim.x + threadIdx.x;
  f32x4 v0 = *(const f32x4*)&in[(size_t)i * 8];
  f32x4 v1 = *(const f32x4*)&in[(size_t)i * 8 + 4];
  bf16x8 o;
  o[0] = (bf16_t)v0[0]; o[1] = (bf16_t)v0[1]; o[2] = (bf16_t)v0[2]; o[3] = (bf16_t)v0[3];
  o[4] = (bf16_t)v1[0]; o[5] = (bf16_t)v1[1]; o[6] = (bf16_t)v1[2]; o[7] = (bf16_t)v1[3];
  *(bf16x8*)&out[(size_t)i * 8] = o;
}

// ---------------- K0b: weight [512][512] f32 -> wT bf16 (transpose) ----------------
__global__ void transpose_cvt_kernel(const float* __restrict__ in,
                                     bf16_t* __restrict__ out) {
  __shared__ float t[32][33];
  const int ti = blockIdx.x;
  const int tj = blockIdx.y;
  const int c = threadIdx.x & 31;
  const int r0 = threadIdx.x >> 5;
  #pragma unroll
  for (int p = 0; p < 4; ++p) {
    int r = r0 + p * 8;
    t[r][c] = in[(size_t)(ti * 32 + r) * 512 + tj * 32 + c];
  }
  __syncthreads();
  #pragma unroll
  for (int p = 0; p < 4; ++p) {
    int r = r0 + p * 8;
    out[(size_t)(tj * 32 + r) * 512 + ti * 32 + c] = (bf16_t)t[c][r];
  }
}

// ---------------- K1 GEMM-BT (bf16 A, stage-ahead dbuf) — unchanged ----------------
template<int NI>
__global__ __launch_bounds__(512, 2) void gemm_bt32_kernel(
    const bf16_t* __restrict__ Ab, const bf16_t* __restrict__ Bt,
    bf16_t* __restrict__ Cv, int nmt, int nnt, int ksteps,
    int lda, int ldb, int ldc) {
  constexpr int BM = 128, BK = 32, BN = NI * 64;
  __shared__ alignas(16) bf16_t Al[2][BM * BK];
  __shared__ alignas(16) bf16_t Bl[2][BN * BK];

  const int tid  = threadIdx.x;
  const int lane = tid & 63;
  const int w    = tid >> 6;
  const int wr   = w >> 2;
  const int wc   = w & 3;

  const int nwg = gridDim.x;
  const int cpx = nwg >> 3;
  const int bid = blockIdx.x;
  const int swz = (bid & 7) * cpx + (bid >> 3);
  const int nt  = swz / nmt;
  const int mt  = swz - nt * nmt;
  const int row0 = mt * BM;
  const int col0 = nt * BN;

  f32x4 acc[4][NI];
  #pragma unroll
  for (int mi = 0; mi < 4; ++mi)
    #pragma unroll
    for (int ni = 0; ni < NI; ++ni)
      acc[mi][ni] = (f32x4){0.f, 0.f, 0.f, 0.f};

  const int r4   = tid >> 2;
  const int g4   = tid & 3;
  const int gsrc = g4 ^ (r4 & 3);

  auto stageB = [&](int b, int k0) {
    #pragma unroll
    for (int i = 0; i < NI / 2; ++i)
      gload_lds16(&Bt[(size_t)(col0 + r4 + i * 128) * ldb + k0 + gsrc * 8],
                  &Bl[b][(tid + i * 512) * 8]);
  };
  auto stageA = [&](int b, int k0) {
    gload_lds16(&Ab[(size_t)(row0 + r4) * lda + k0 + gsrc * 8],
                &Al[b][tid * 8]);
  };

  stageB(0, 0);
  stageA(0, 0);
  __syncthreads();

  int cur = 0;
  for (int kt = 0; kt < ksteps; ++kt) {
    if (kt + 1 < ksteps) {
      stageB(cur ^ 1, (kt + 1) * BK);
      stageA(cur ^ 1, (kt + 1) * BK);
    }
    const int frow = lane & 15;
    const int gk = lane >> 4;
    bf16x8 a[4], b[NI];
    #pragma unroll
    for (int mi = 0; mi < 4; ++mi) {
      const int r = wr * 64 + mi * 16 + frow;
      a[mi] = *(const bf16x8*)&Al[cur][r * 32 + ((gk ^ (r & 3)) << 3)];
    }
    #pragma unroll
    for (int ni = 0; ni < NI; ++ni) {
      const int r = wc * (NI * 16) + ni * 16 + frow;
      b[ni] = *(const bf16x8*)&Bl[cur][r * 32 + ((gk ^ (r & 3)) << 3)];
    }
    #pragma unroll
    for (int mi = 0; mi < 4; ++mi)
      #pragma unroll
      for (int ni = 0; ni < NI; ++ni)
        acc[mi][ni] = __builtin_amdgcn_mfma_f32_16x16x32_bf16(a[mi], b[ni], acc[mi][ni], 0, 0, 0);
    __syncthreads();
    cur ^= 1;
  }

  const int rbase = row0 + wr * 64 + ((lane >> 4) << 2);
  const int cbase = col0 + wc * (NI * 16) + (lane & 15);
  #pragma unroll
  for (int mi = 0; mi < 4; ++mi)
    #pragma unroll
    for (int ni = 0; ni < NI; ++ni)
      #pragma unroll
      for (int j = 0; j < 4; ++j)
        Cv[(size_t)(rbase + mi * 16 + j) * ldc + cbase + ni * 16] =
            (bf16_t)acc[mi][ni][j];
}

// ---------------- K2 m97-geometry: adj(f32) @ fwT^T ----------------
// BM=BN=128, BK=32, 256 threads = 4 waves (2M x 2N), wave tile 64x64,
// acc[4][4]=64 VGPR. LDS 32 KB dbuf (A 2x8KB bf16 + B 2x8KB).
// __launch_bounds__(256,3) -> 3 blocks/CU resident, 12 waves/CU: m97's
// occupancy geometry — desynced small blocks cover each other's barrier
// drains (m114 mechanism). Simple R5-proven 2-phase stage-ahead loop.
// k-split 4, grid = 64mt x 4nt x 4ks = 1024, ks-major XCD map: per-XCD
// fwT K-slice 2MB L2-resident; nt-quads co-located -> adj HBM-read once.
// Swizzle: rows 64B/4 granules, LDS slot g^(r&3); B source-preswizzled
// (linear gload_lds dest), A reg-staged f32->bf16 w/ swizzled ds_write.
// EPI 3: bf16 partial @ Cv+ks*pstride; EPI 2: f32 atomicAdd fallback.
template<int EPI>
__global__ __launch_bounds__(256, 3) void gemm_k2_m97(
    const float* __restrict__ adj, const bf16_t* __restrict__ Bt,
    void* __restrict__ Cv, size_t pstride) {
  constexpr int KSTEPS = 64;
  __shared__ alignas(16) bf16_t Al[2][128 * 32];
  __shared__ alignas(16) bf16_t Bl[2][128 * 32];

  const int tid  = threadIdx.x;
  const int lane = tid & 63;
  const int w    = tid >> 6;     // 0..3
  const int wr   = w >> 1;       // 0..1
  const int wc   = w & 1;        // 0..1

  const int bid = blockIdx.x;                 // grid 1024
  const int swz = (bid & 7) * 128 + (bid >> 3);
  const int ks  = swz >> 8;                   // 0..3 (2 XCDs per ks)
  const int rem = swz & 255;
  const int mt  = rem >> 2;                   // 0..63
  const int nt  = rem & 3;                    // 0..3 (adjacent on one XCD)
  const int row0 = mt * 128;
  const int col0 = nt * 128;
  const int kbase = ks * 2048;

  f32x4 acc[4][4];
  #pragma unroll
  for (int mi = 0; mi < 4; ++mi)
    #pragma unroll
    for (int ni = 0; ni < 4; ++ni)
      acc[mi][ni] = (f32x4){0.f, 0.f, 0.f, 0.f};

  // A staging: thread -> row ar = tid>>1, k-half ah = tid&1 (16 f32 = 64 B)
  const int ar = tid >> 1;
  const int ah = tid & 1;
  f32x4 apref[4];

  auto loadA = [&](int t) {
    const float* p = &adj[(size_t)(row0 + ar) * 8192 + kbase + t * 32 + ah * 16];
    apref[0] = ((const f32x4*)p)[0];
    apref[1] = ((const f32x4*)p)[1];
    apref[2] = ((const f32x4*)p)[2];
    apref[3] = ((const f32x4*)p)[3];
  };
  auto writeA = [&](int b) {
    bf16x8 v0, v1;
    v0[0] = (bf16_t)apref[0][0]; v0[1] = (bf16_t)apref[0][1];
    v0[2] = (bf16_t)apref[0][2]; v0[3] = (bf16_t)apref[0][3];
    v0[4] = (bf16_t)apref[1][0]; v0[5] = (bf16_t)apref[1][1];
    v0[6] = (bf16_t)apref[1][2]; v0[7] = (bf16_t)apref[1][3];
    v1[0] = (bf16_t)apref[2][0]; v1[1] = (bf16_t)apref[2][1];
    v1[2] = (bf16_t)apref[2][2]; v1[3] = (bf16_t)apref[2][3];
    v1[4] = (bf16_t)apref[3][0]; v1[5] = (bf16_t)apref[3][1];
    v1[6] = (bf16_t)apref[3][2]; v1[7] = (bf16_t)apref[3][3];
    const int g0 = ah * 2, g1 = ah * 2 + 1;
    *(bf16x8*)&Al[b][ar * 32 + ((g0 ^ (ar & 3)) << 3)] = v0;
    *(bf16x8*)&Al[b][ar * 32 + ((g1 ^ (ar & 3)) << 3)] = v1;
  };
  auto stageB = [&](int t, int b) {
    #pragma unroll
    for (int i = 0; i < 2; ++i) {
      const int d = tid + i * 256;     // linear dest granule
      const int r = d >> 2;
      const int s = d & 3;
      gload_lds16(&Bt[(size_t)(col0 + r) * 8192 + kbase + t * 32 + ((s ^ (r & 3)) << 3)],
                  &Bl[b][(size_t)d * 8]);
    }
  };

  // ---- prologue ----
  stageB(0, 0);
  loadA(0);
  writeA(0);
  loadA(1);
  __syncthreads();

  const int frow = lane & 15;
  const int gk   = lane >> 4;
  int cur = 0;
  for (int t = 0; t < KSTEPS; ++t) {
    if (t + 1 < KSTEPS) {
      stageB(t + 1, cur ^ 1);
      writeA(cur ^ 1);                     // apref holds tile t+1
      if (t + 2 < KSTEPS) loadA(t + 2);    // issue f32 loads for t+2
    }
    bf16x8 a[4], b[4];
    #pragma unroll
    for (int mi = 0; mi < 4; ++mi) {
      const int r = wr * 64 + mi * 16 + frow;
      a[mi] = *(const bf16x8*)&Al[cur][r * 32 + ((gk ^ (r & 3)) << 3)];
    }
    #pragma unroll
    for (int ni = 0; ni < 4; ++ni) {
      const int r = wc * 64 + ni * 16 + frow;
      b[ni] = *(const bf16x8*)&Bl[cur][r * 32 + ((gk ^ (r & 3)) << 3)];
    }
    #pragma unroll
    for (int mi = 0; mi < 4; ++mi)
      #pragma unroll
      for (int ni = 0; ni < 4; ++ni)
        acc[mi][ni] = __builtin_amdgcn_mfma_f32_16x16x32_bf16(a[mi], b[ni], acc[mi][ni], 0, 0, 0);
    __syncthreads();
    cur ^= 1;
  }

  // epilogue: C/D layout col=lane&15, row=(lane>>4)*4+reg  [m89-verified]
  const int rbase = row0 + wr * 64 + ((lane >> 4) << 2);
  const int cbase = col0 + wc * 64 + (lane & 15);
  if constexpr (EPI == 3) {
    bf16_t* C = (bf16_t*)Cv + (size_t)ks * pstride;
    #pragma unroll
    for (int mi = 0; mi < 4; ++mi)
      #pragma unroll
      for (int ni = 0; ni < 4; ++ni)
        #pragma unroll
        for (int j = 0; j < 4; ++j)
          C[(size_t)(rbase + mi * 16 + j) * 512 + cbase + ni * 16] =
              (bf16_t)acc[mi][ni][j];
  } else {
    float* C = (float*)Cv;
    #pragma unroll
    for (int mi = 0; mi < 4; ++mi)
      #pragma unroll
      for (int ni = 0; ni < 4; ++ni)
        #pragma unroll
        for (int j = 0; j < 4; ++j)
          atomicAdd(&C[(size_t)(rbase + mi * 16 + j) * 512 + cbase + ni * 16],
                    acc[mi][ni][j]);
  }
}

// ---------------- reduce 4 bf16 partials + relu -> f32 ----------------
__global__ void reduce4_relu_kernel(const bf16_t* __restrict__ part,
                                    size_t pstride, float* __restrict__ out) {
  const size_t i8 = ((size_t)blockIdx.x * blockDim.x + threadIdx.x) * 8;
  float s[8];
  #pragma unroll
  for (int j = 0; j < 8; ++j) s[j] = 0.f;
  #pragma unroll
  for (int p = 0; p < 4; ++p) {
    bf16x8 v = *(const bf16x8*)&part[p * pstride + i8];
    #pragma unroll
    for (int j = 0; j < 8; ++j) s[j] += (float)v[j];
  }
  f32x4 r0, r1;
  r0[0] = fmaxf(s[0], 0.f); r0[1] = fmaxf(s[1], 0.f);
  r0[2] = fmaxf(s[2], 0.f); r0[3] = fmaxf(s[3], 0.f);
  r1[0] = fmaxf(s[4], 0.f); r1[1] = fmaxf(s[5], 0.f);
  r1[2] = fmaxf(s[6], 0.f); r1[3] = fmaxf(s[7], 0.f);
  *(f32x4*)&out[i8] = r0;
  *(f32x4*)&out[i8 + 4] = r1;
}

// ---------------- in-place relu (atomic fallback) ----------------
__global__ void relu_inplace_kernel(float* __restrict__ out) {
  const size_t i = ((size_t)blockIdx.x * blockDim.x + threadIdx.x) * 4;
  f32x4 a = *(const f32x4*)&out[i];
  f32x4 r;
  r[0] = fmaxf(a[0], 0.f); r[1] = fmaxf(a[1], 0.f);
  r[2] = fmaxf(a[2], 0.f); r[3] = fmaxf(a[3], 0.f);
  *(f32x4*)&out[i] = r;
}

extern "C" void kernel_launch(void* const* d_in, const int* in_sizes, int n_in,
                              void* d_out, int out_size, void* d_ws, size_t ws_size,
                              hipStream_t stream) {
  const int N = 8192, D = 512;
  const float* features = (const float*)d_in[0];  // [N][D]
  const float* adj      = (const float*)d_in[1];  // [N][N]
  const float* weight   = (const float*)d_in[2];  // [D][D]
  float* out = (float*)d_out;                     // [N][D] f32

  char* ws = (char*)d_ws;
  bf16_t* fb16 = (bf16_t*)ws;                                    // 8.39 MB
  bf16_t* wT   = (bf16_t*)(ws + (size_t)N * D * 2);              // 0.52 MB
  bf16_t* fwT  = (bf16_t*)(ws + (size_t)N * D * 2 + (size_t)D * D * 2);  // 8.39 MB
  const size_t base_bytes = (size_t)N * D * 2 * 2 + (size_t)D * D * 2;   // 17.3 MB
  bf16_t* part = (bf16_t*)(ws + base_bytes);      // 4 x 8.39 MB bf16 partials
  const size_t pstride = (size_t)N * D;
  const bool have_part = ws_size >= base_bytes + 4 * pstride * sizeof(bf16_t);

  // K0a: features f32 -> bf16
  cvt_f32_bf16_kernel<<<(N * D / 8) / 256, 256, 0, stream>>>(features, fb16);
  // K0b: wT[dout][din] = weight[din][dout]
  transpose_cvt_kernel<<<dim3(16, 16), 256, 0, stream>>>(weight, wT);
  // K1: fwT[dout][node] = wT @ fb16^T   M=512 (nmt=4), N=8192 (nnt=64, BN=128)
  gemm_bt32_kernel<2><<<256, 512, 0, stream>>>(wT, fb16, fwT,
                                               4, 64, 16, 512, 512, 8192);
  // K2: relu(adj @ fwT^T), m97 geometry (4-wave blocks, 3/CU), grid 1024
  if (have_part) {
    gemm_k2_m97<3><<<1024, 256, 0, stream>>>(adj, fwT, part, pstride);
    reduce4_relu_kernel<<<(N * D / 8) / 512, 512, 0, stream>>>(part, pstride, out);
  } else {
    hipMemsetAsync(d_out, 0, (size_t)N * D * sizeof(float), stream);
    gemm_k2_m97<2><<<1024, 256, 0, stream>>>(adj, fwT, out, 0);
    relu_inplace_kernel<<<(N * D / 4) / 512, 512, 0, stream>>>(out);
  }
}

// Round 9
// 137.133 us; speedup vs baseline: 1.2420x; 1.2420x over previous
//
#include <hip/hip_runtime.h>
#include <hip/hip_bf16.h>
#include <stdint.h>

typedef __bf16 bf16_t;
typedef __bf16 bf16x4 __attribute__((ext_vector_type(4)));
typedef __bf16 bf16x8 __attribute__((ext_vector_type(8)));
typedef float  f32x4  __attribute__((ext_vector_type(4)));

#define AS_GLOBAL __attribute__((address_space(1)))
#define AS_LDS    __attribute__((address_space(3)))

__device__ __forceinline__ void gload_lds16(const void* g, void* l) {
  __builtin_amdgcn_global_load_lds((const AS_GLOBAL void*)g,
                                   (AS_LDS void*)l, 16, 0, 0);
}

// ---------------- K0a: f32 -> bf16 elementwise (8 elems/thread) ----------------
__global__ void cvt_f32_bf16_kernel(const float* __restrict__ in,
                                    bf16_t* __restrict__ out) {
  const int i = blockIdx.x * blockDim.x + threadIdx.x;
  f32x4 v0 = *(const f32x4*)&in[(size_t)i * 8];
  f32x4 v1 = *(const f32x4*)&in[(size_t)i * 8 + 4];
  bf16x8 o;
  o[0] = (bf16_t)v0[0]; o[1] = (bf16_t)v0[1]; o[2] = (bf16_t)v0[2]; o[3] = (bf16_t)v0[3];
  o[4] = (bf16_t)v1[0]; o[5] = (bf16_t)v1[1]; o[6] = (bf16_t)v1[2]; o[7] = (bf16_t)v1[3];
  *(bf16x8*)&out[(size_t)i * 8] = o;
}

// ---------------- K0b: weight [512][512] f32 -> wT [512][512] bf16 (transpose) ----------------
__global__ void transpose_cvt_kernel(const float* __restrict__ in,
                                     bf16_t* __restrict__ out) {
  __shared__ float t[32][33];
  const int ti = blockIdx.x;  // din tile
  const int tj = blockIdx.y;  // dout tile
  const int c = threadIdx.x & 31;
  const int r0 = threadIdx.x >> 5;  // 0..7
  #pragma unroll
  for (int p = 0; p < 4; ++p) {
    int r = r0 + p * 8;
    t[r][c] = in[(size_t)(ti * 32 + r) * 512 + tj * 32 + c];
  }
  __syncthreads();
  #pragma unroll
  for (int p = 0; p < 4; ++p) {
    int r = r0 + p * 8;
    out[(size_t)(tj * 32 + r) * 512 + ti * 32 + c] = (bf16_t)t[c][r];
  }
}

// ---------------- GEMM-BT: C[m][n] (+)= sum_k A[m][k] * Bt[n][k] ----------------
// R5-proven structure. BM=128, BK=32, BN = NI*64; 512 threads = 8 waves as
// 2M x 4N; wave tile 64 x NI*16, acc[4][NI]. Rows are 64 B in LDS (4 x 16B
// granules); granule g of row r lives at slot g^(r&3) -> conflict-free b128
// frag reads. B staged by global_load_lds (linear dest, SOURCE granule
// pre-swizzled); A is either bf16 (gload_lds) or f32 (reg-staged + cvt,
// swizzled ds_write, 1-step-ahead HBM prefetch, NON-TEMPORAL loads so the
// 256 MB adj stream does not evict the L2-resident fwT slice).
// K-split: block ks covers K-range [ks*ksteps*32, ...). XCD chunk-swizzle is
// ks-major so each XCD's Bt K-slice (2 MB < 4 MB L2) stays L2-resident.
// EPI: 0 = bf16 store; 2 = f32 atomicAdd into pre-zeroed Cv; 3 = bf16 partial
// NON-TEMPORAL store at Cv + ks*pstride (write-once traffic, keep out of L2).
template<int A_IS_F32, int EPI, int NI>
__global__ __launch_bounds__(512, 2) void gemm_bt32_kernel(
    const void* __restrict__ Av, const bf16_t* __restrict__ Bt,
    void* __restrict__ Cv, int nmt, int nnt, int ksteps,
    int lda, int ldb, int ldc, size_t pstride) {
  constexpr int BM = 128, BK = 32, BN = NI * 64;
  __shared__ alignas(16) bf16_t Al[2][BM * BK];  // 2 x 8 KB
  __shared__ alignas(16) bf16_t Bl[2][BN * BK];  // 2 x BN/16 KB

  const int tid  = threadIdx.x;
  const int lane = tid & 63;
  const int w    = tid >> 6;
  const int wr   = w >> 2;  // 0..1 (M)
  const int wc   = w & 3;   // 0..3 (N)

  // XCD chunk-swizzle (grid divisible by 8), ks-major ordering
  const int nwg = gridDim.x;
  const int cpx = nwg >> 3;
  const int bid = blockIdx.x;
  const int swz = (bid & 7) * cpx + (bid >> 3);
  const int ks  = swz / (nmt * nnt);
  const int r_  = swz - ks * (nmt * nnt);
  const int nt  = r_ / nmt;
  const int mt  = r_ - nt * nmt;
  const int row0 = mt * BM;
  const int col0 = nt * BN;
  const int kst  = ks * ksteps * BK;

  f32x4 acc[4][NI];
  #pragma unroll
  for (int mi = 0; mi < 4; ++mi)
    #pragma unroll
    for (int ni = 0; ni < NI; ++ni)
      acc[mi][ni] = (f32x4){0.f, 0.f, 0.f, 0.f};

  const float*  Af = (const float*)Av;
  const bf16_t* Ab = (const bf16_t*)Av;

  // staging geometry: granule d = tid + i*512; row = d>>2, slot = d&3,
  // global source granule = slot ^ (row&3)  (row&3 invariant under +128 rows)
  const int r4   = tid >> 2;          // 0..127
  const int g4   = tid & 3;
  const int gsrc = g4 ^ (r4 & 3);

  f32x4 apref0, apref1;

  auto stageB = [&](int b, int k0) {
    #pragma unroll
    for (int i = 0; i < NI / 2; ++i)
      gload_lds16(&Bt[(size_t)(col0 + r4 + i * 128) * ldb + kst + k0 + gsrc * 8],
                  &Bl[b][(tid + i * 512) * 8]);
  };
  auto stageA16 = [&](int b, int k0) {
    gload_lds16(&Ab[(size_t)(row0 + r4) * lda + kst + k0 + gsrc * 8],
                &Al[b][tid * 8]);
  };
  auto loadA = [&](int k0) {
    const float* p = &Af[(size_t)(row0 + r4) * lda + kst + k0 + g4 * 8];
    apref0 = __builtin_nontemporal_load((const f32x4*)p);       // nt: bypass L2
    apref1 = __builtin_nontemporal_load(((const f32x4*)p) + 1); // residency
  };
  auto writeA = [&](int b) {
    bf16x8 v;
    v[0] = (bf16_t)apref0[0]; v[1] = (bf16_t)apref0[1];
    v[2] = (bf16_t)apref0[2]; v[3] = (bf16_t)apref0[3];
    v[4] = (bf16_t)apref1[0]; v[5] = (bf16_t)apref1[1];
    v[6] = (bf16_t)apref1[2]; v[7] = (bf16_t)apref1[3];
    *(bf16x8*)&Al[b][r4 * 32 + ((g4 ^ (r4 & 3)) << 3)] = v;
  };

  // ---- prologue ----
  stageB(0, 0);
  if constexpr (A_IS_F32) {
    loadA(0);
    writeA(0);
    if (ksteps > 1) loadA(BK);
  } else {
    stageA16(0, 0);
  }
  __syncthreads();

  int cur = 0;
  for (int kt = 0; kt < ksteps; ++kt) {
    if (kt + 1 < ksteps) {
      stageB(cur ^ 1, (kt + 1) * BK);
      if constexpr (A_IS_F32) {
        writeA(cur ^ 1);                        // apref holds tile kt+1
        if (kt + 2 < ksteps) loadA((kt + 2) * BK);
      } else {
        stageA16(cur ^ 1, (kt + 1) * BK);
      }
    }
    // frags: k-granule = lane>>4
    const int frow = lane & 15;
    const int gk = lane >> 4;
    bf16x8 a[4], b[NI];
    #pragma unroll
    for (int mi = 0; mi < 4; ++mi) {
      const int r = wr * 64 + mi * 16 + frow;
      a[mi] = *(const bf16x8*)&Al[cur][r * 32 + ((gk ^ (r & 3)) << 3)];
    }
    #pragma unroll
    for (int ni = 0; ni < NI; ++ni) {
      const int r = wc * (NI * 16) + ni * 16 + frow;
      b[ni] = *(const bf16x8*)&Bl[cur][r * 32 + ((gk ^ (r & 3)) << 3)];
    }
    #pragma unroll
    for (int mi = 0; mi < 4; ++mi)
      #pragma unroll
      for (int ni = 0; ni < NI; ++ni)
        acc[mi][ni] = __builtin_amdgcn_mfma_f32_16x16x32_bf16(a[mi], b[ni], acc[mi][ni], 0, 0, 0);
    __syncthreads();
    cur ^= 1;
  }

  // epilogue: C/D layout col=lane&15, row=(lane>>4)*4+reg  [m89-verified]
  const int rbase = row0 + wr * 64 + ((lane >> 4) << 2);
  const int cbase = col0 + wc * (NI * 16) + (lane & 15);
  if constexpr (EPI == 3) {           // bf16 partial, non-temporal store
    bf16_t* C = (bf16_t*)Cv + (size_t)ks * pstride;
    #pragma unroll
    for (int mi = 0; mi < 4; ++mi)
      #pragma unroll
      for (int ni = 0; ni < NI; ++ni)
        #pragma unroll
        for (int j = 0; j < 4; ++j) {
          short sv = __builtin_bit_cast(short, (bf16_t)acc[mi][ni][j]);
          __builtin_nontemporal_store(
              sv, (short*)&C[(size_t)(rbase + mi * 16 + j) * ldc + cbase + ni * 16]);
        }
  } else if constexpr (EPI == 2) {    // atomic accumulate into zeroed out
    float* C = (float*)Cv;
    #pragma unroll
    for (int mi = 0; mi < 4; ++mi)
      #pragma unroll
      for (int ni = 0; ni < NI; ++ni)
        #pragma unroll
        for (int j = 0; j < 4; ++j)
          atomicAdd(&C[(size_t)(rbase + mi * 16 + j) * ldc + cbase + ni * 16],
                    acc[mi][ni][j]);
  } else {                            // bf16 store (K1)
    bf16_t* C = (bf16_t*)Cv;
    #pragma unroll
    for (int mi = 0; mi < 4; ++mi)
      #pragma unroll
      for (int ni = 0; ni < NI; ++ni)
        #pragma unroll
        for (int j = 0; j < 4; ++j)
          C[(size_t)(rbase + mi * 16 + j) * ldc + cbase + ni * 16] =
              (bf16_t)acc[mi][ni][j];
  }
}

// ---------------- reduce 4 bf16 partials + relu -> f32 ----------------
__global__ void reduce4_relu_kernel(const bf16_t* __restrict__ part,
                                    size_t pstride, float* __restrict__ out) {
  const size_t i8 = ((size_t)blockIdx.x * blockDim.x + threadIdx.x) * 8;
  float s[8];
  #pragma unroll
  for (int j = 0; j < 8; ++j) s[j] = 0.f;
  #pragma unroll
  for (int p = 0; p < 4; ++p) {
    bf16x8 v = *(const bf16x8*)&part[p * pstride + i8];
    #pragma unroll
    for (int j = 0; j < 8; ++j) s[j] += (float)v[j];
  }
  f32x4 r0, r1;
  r0[0] = fmaxf(s[0], 0.f); r0[1] = fmaxf(s[1], 0.f);
  r0[2] = fmaxf(s[2], 0.f); r0[3] = fmaxf(s[3], 0.f);
  r1[0] = fmaxf(s[4], 0.f); r1[1] = fmaxf(s[5], 0.f);
  r1[2] = fmaxf(s[6], 0.f); r1[3] = fmaxf(s[7], 0.f);
  *(f32x4*)&out[i8] = r0;
  *(f32x4*)&out[i8 + 4] = r1;
}

// ---------------- in-place relu (atomic fallback) ----------------
__global__ void relu_inplace_kernel(float* __restrict__ out) {
  const size_t i = ((size_t)blockIdx.x * blockDim.x + threadIdx.x) * 4;
  f32x4 a = *(const f32x4*)&out[i];
  f32x4 r;
  r[0] = fmaxf(a[0], 0.f); r[1] = fmaxf(a[1], 0.f);
  r[2] = fmaxf(a[2], 0.f); r[3] = fmaxf(a[3], 0.f);
  *(f32x4*)&out[i] = r;
}

extern "C" void kernel_launch(void* const* d_in, const int* in_sizes, int n_in,
                              void* d_out, int out_size, void* d_ws, size_t ws_size,
                              hipStream_t stream) {
  const int N = 8192, D = 512;
  const float* features = (const float*)d_in[0];  // [N][D]
  const float* adj      = (const float*)d_in[1];  // [N][N]
  const float* weight   = (const float*)d_in[2];  // [D][D]
  float* out = (float*)d_out;                     // [N][D] f32

  char* ws = (char*)d_ws;
  bf16_t* fb16 = (bf16_t*)ws;                                    // 8.39 MB
  bf16_t* wT   = (bf16_t*)(ws + (size_t)N * D * 2);              // 0.52 MB
  bf16_t* fwT  = (bf16_t*)(ws + (size_t)N * D * 2 + (size_t)D * D * 2);  // 8.39 MB
  const size_t base_bytes = (size_t)N * D * 2 * 2 + (size_t)D * D * 2;   // 17.3 MB
  bf16_t* part = (bf16_t*)(ws + base_bytes);      // 4 x 8.39 MB bf16 partials
  const size_t pstride = (size_t)N * D;           // elements per partial
  const bool have_part = ws_size >= base_bytes + 4 * pstride * sizeof(bf16_t);

  // K0a: features f32 -> bf16
  cvt_f32_bf16_kernel<<<(N * D / 8) / 256, 256, 0, stream>>>(features, fb16);
  // K0b: wT[dout][din] = weight[din][dout]
  transpose_cvt_kernel<<<dim3(16, 16), 256, 0, stream>>>(weight, wT);
  // K1: fwT[dout][node] = wT @ fb16^T   M=512 (nmt=4), N=8192 (nnt=64, BN=128),
  //     K=512 (16 steps, no k-split).  grid = 4*64 = 256
  gemm_bt32_kernel<0, 0, 2><<<256, 512, 0, stream>>>(wT, fb16, fwT,
                                                     4, 64, 16, 512, 512, 8192, 0);
  // K2: relu(adj @ fwT^T): M=8192 (nmt=64), N=512 (nnt=1, BN=512), K=8192,
  //     k-split 4 (ksteps=64) -> grid = 64*4 = 256; bf16 partials + reduce.
  //     adj loads non-temporal -> fwT K-slice stays L2-resident per XCD.
  if (have_part) {
    gemm_bt32_kernel<1, 3, 8><<<256, 512, 0, stream>>>(adj, fwT, part,
                                                       64, 1, 64, 8192, 8192, 512, pstride);
    reduce4_relu_kernel<<<(N * D / 8) / 512, 512, 0, stream>>>(part, pstride, out);
  } else {
    hipMemsetAsync(d_out, 0, (size_t)N * D * sizeof(float), stream);
    gemm_bt32_kernel<1, 2, 8><<<256, 512, 0, stream>>>(adj, fwT, out,
                                                       64, 1, 64, 8192, 8192, 512, 0);
    relu_inplace_kernel<<<(N * D / 4) / 512, 512, 0, stream>>>(out);
  }
}